// Round 14
// baseline (119.539 us; speedup 1.0000x reference)
//
#include <hip/hip_runtime.h>

// QCNN: 8 qubits, 256 amps. R14: f16x2 state, FOUR elements per wave.
// R13 (2 elem) showed VALU 85% / DS 46% with ~15% latency bubbles ->
// 4 independent gate chains per wave to fill them. Lane l holds amps
// i=(l<<2)|j per element: A=(j0,j1), B=(j2,j3) as _Float16 x2.
// q0..q5 lane bits (xor 1,2 = DPP; 4,8,16 = swizzle; 32 = bpermute);
// q6 = reg, q7 = component. fp32: angles/sincos, expvals, reduce, MLP.
// All state arrays are [4] indexed only by unrolled loop vars (SROA-safe;
// R9's runtime-indexed arrays caused scratch demotion).

#define NQ 8
typedef _Float16 h2 __attribute__((ext_vector_type(2)));

__device__ __forceinline__ float h2f(h2 v){ return __builtin_bit_cast(float, v); }
__device__ __forceinline__ h2 f2h(float v){ return __builtin_bit_cast(h2, v); }
__device__ __forceinline__ h2 u2h(unsigned u){ return __builtin_bit_cast(h2, u); }
__device__ __forceinline__ h2 negh(h2 v){ return __builtin_bit_cast(h2, __builtin_bit_cast(unsigned, v) ^ 0x80008000u); }
__device__ __forceinline__ h2 mk(float x){ _Float16 h=(_Float16)x; return (h2){h,h}; }
__device__ __forceinline__ h2 mk2(float a, float b){ return (h2){(_Float16)a,(_Float16)b}; }
__device__ __forceinline__ h2 fma2h(h2 a, h2 b, h2 c){ return __builtin_elementwise_fma(a,b,c); }
__device__ __forceinline__ h2 swp(h2 v){ return __builtin_shufflevector(v,v,1,0); }

template<int CTRL>
__device__ __forceinline__ float dppf(float v){
    return __int_as_float(__builtin_amdgcn_mov_dpp(__float_as_int(v), CTRL, 0xF, 0xF, true));
}
template<int M>
__device__ __forceinline__ float sx(float v){
    if constexpr (M==1)       return dppf<0xB1>(v);          // quad_perm
    else if constexpr (M==2)  return dppf<0x4E>(v);          // quad_perm
    else if constexpr (M==32) return __shfl_xor(v, 32, 64);  // bpermute
    else return __int_as_float(__builtin_amdgcn_ds_swizzle(__float_as_int(v), (M<<10)|0x1F)); // 4,8,16
}
__device__ __forceinline__ float bperm(int ba, float v){
    return __int_as_float(__builtin_amdgcn_ds_bpermute(ba, __float_as_int(v)));
}
__device__ __forceinline__ void cmulh(h2&R, h2&I, h2 C, h2 S, h2 nS){
    h2 nR = fma2h(C, R, nS*I);
    I = fma2h(C, I, S*R);
    R = nR;
}

#define NE 4
#define FOR_E _Pragma("unroll") for (int e = 0; e < NE; ++e)

// ---- prep: fp32 constants -> f16x2-packed uints in ws (unchanged R12) ----
__global__ void qcnn_prep(const float* __restrict__ crx,
                          const float* __restrict__ u3p,
                          unsigned* __restrict__ ws){
    if (threadIdx.x==0 && blockIdx.x==0){
        auto PK=[](float lo, float hi)->unsigned{
            unsigned a=__builtin_bit_cast(unsigned short,(_Float16)lo);
            unsigned b=__builtin_bit_cast(unsigned short,(_Float16)hi);
            return a | (b<<16);
        };
        float sc0,cc0,sc1,cc1;
        __sincosf(0.5f*crx[0],&sc0,&cc0);
        __sincosf(0.5f*crx[1],&sc1,&cc1);
        ws[0]=PK(cc0,cc0); ws[1]=PK(sc0,sc0); ws[2]=PK(cc1,cc1); ws[3]=PK(sc1,sc1);
        float th0=u3p[0], ph0=u3p[1], lm0=u3p[2];
        float ust0,uct0; __sincosf(0.5f*th0,&ust0,&uct0);
        ws[4]=PK(uct0,uct0); ws[5]=PK(ust0,ust0); ws[6]=PK(-ust0,-ust0); ws[7]=PK(-ust0,ust0);
        float th1=u3p[3], ph1=u3p[4], lm1=u3p[5];
        float ust1,uct1; __sincosf(0.5f*th1,&ust1,&uct1);
        float sl1,cl1;   __sincosf(lm1,&sl1,&cl1);
        float sp1,cp1;   __sincosf(ph1,&sp1,&cp1);
        ws[8]=PK(uct1,uct1); ws[9]=PK(ust1,ust1); ws[10]=PK(-ust1,-ust1);
        ws[11]=PK(cl1,cl1); ws[12]=PK(sl1,sl1); ws[13]=PK(cp1,cp1); ws[14]=PK(sp1,sp1);
        float cpl1=cp1*cl1-sp1*sl1, spl1=sp1*cl1+cp1*sl1;
        float u01r=-ust1*cl1, u01i=-ust1*sl1;
        float u10r= ust1*cp1, u10i= ust1*sp1;
        float u11r= uct1*cpl1, u11i= uct1*spl1;
        ws[15]=PK(uct1,u11r); ws[16]=PK(u01r,u10r); ws[17]=PK(0.f,-u11i);
        ws[18]=PK(-u01i,-u10i); ws[19]=PK(0.f,u11i); ws[20]=PK(u01i,u10i);
        for(int k=0;k<4;++k){
            float kf=(float)k, sA,cA,sB,cB,sA2,cA2,sB2,cB2;
            __sincosf(lm0*kf,      &sA,&cA);
            __sincosf(lm0*(kf+1.f),&sB,&cB);
            __sincosf(ph0*kf,      &sA2,&cA2);
            __sincosf(ph0*(kf+1.f),&sB2,&cB2);
            unsigned* q = ws + 24 + k*4;
            q[0]=PK(cA,cB); q[1]=PK(sA,sB); q[2]=PK(cA2,cB2); q[3]=PK(sA2,sB2);
        }
    }
}

__global__ __launch_bounds__(256) void qcnn_kernel(
    const float* __restrict__ x,
    const unsigned* __restrict__ wsu,
    const float* __restrict__ w1,
    const float* __restrict__ b1,
    const float* __restrict__ w2,
    const float* __restrict__ b2,
    float* __restrict__ out,
    int Btot)
{
    const int gtid = blockIdx.x*256 + threadIdx.x;
    const int wv = gtid >> 6;
    const int l = threadIdx.x & 63;
    const int e0 = wv * NE;
    if (e0 >= Btot) return;
    const bool L5=(l>>5)&1, L4=(l>>4)&1, L3=(l>>3)&1, L2=(l>>2)&1, L1=(l>>1)&1, L0=l&1;

    // fused-CNOT per-lane constants (verified R2-R13)
    const bool pb = __builtin_popcount(l) & 1;
    const int ba0 = (((l&32)|((l^(l>>1))&31)) << 2);
    const int ba1 = ba0 ^ (48<<2);

    // per-element angles (fp32) -> f16 gate coefficients; init product state
    h2 cH[NE][6], tsH[NE][6];
    h2 c6h[NE], s6h[NE], ns6h[NE], c7h[NE], sv7h[NE];
    h2 A[NE], B[NE];
    const bool bits[6]={L5,L4,L3,L2,L1,L0};
    FOR_E {
        const float4* xv = (const float4*)(x + (e0+e)*NQ);
        float4 xa=xv[0], xb=xv[1];
        float ang[8]={xa.x,xa.y,xa.z,xa.w,xb.x,xb.y,xb.z,xb.w};
        float cq[8], sq[8];
#pragma unroll
        for(int q=0;q<8;++q) __sincosf(0.5f*ang[q], &sq[q], &cq[q]);
#pragma unroll
        for(int q=0;q<6;++q){
            cH[e][q]=mk(cq[q]);
            h2 sh=mk(sq[q]);
            tsH[e][q]= bits[q] ? sh : negh(sh);
        }
        c6h[e]=mk(cq[6]); s6h[e]=mk(sq[6]); ns6h[e]=negh(s6h[e]);
        c7h[e]=mk(cq[7]); sv7h[e]=mk2(-sq[7], sq[7]);
        float pl = (L5?sq[0]:cq[0])*(L4?sq[1]:cq[1])*(L3?sq[2]:cq[2])
                 * (L2?sq[3]:cq[3])*(L1?sq[4]:cq[4])*(L0?sq[5]:cq[5]);
        float pc6=pl*cq[6], ps6=pl*sq[6];
        A[e] = mk2(pc6*cq[7], pc6*sq[7]);
        B[e] = mk2(ps6*cq[7], ps6*sq[7]);
    }

    // uniform constants (scalar loads, f16x2-packed -> SGPRs)
    const h2 cc0h=u2h(wsu[0]), sn0h=u2h(wsu[1]), cc1h=u2h(wsu[2]), sn1h=u2h(wsu[3]);
    const h2 nsn0h=negh(sn0h), nsn1h=negh(sn1h);
    const h2 uct0h=u2h(wsu[4]), ust0h=u2h(wsu[5]), nust0h=u2h(wsu[6]), usv0h=u2h(wsu[7]);
    const h2 uct1h=u2h(wsu[8]), ust1h=u2h(wsu[9]), nust1h=u2h(wsu[10]);
    const h2 cl1h=u2h(wsu[11]), sl1h=u2h(wsu[12]), nsl1h=negh(sl1h);
    const h2 cp1h=u2h(wsu[13]), sp1h=u2h(wsu[14]), nsp1h=negh(sp1h);
    const h2 E0h=u2h(wsu[15]), E1h=u2h(wsu[16]), E2h=u2h(wsu[17]);
    const h2 E3h=u2h(wsu[18]), G2h=u2h(wsu[19]), G3h=u2h(wsu[20]);
    const int ki = (int)L4 + (int)L2 + (int)L0;
    uint4 dt = *(const uint4*)(wsu + 24 + ki*4);
    const h2 Clm=u2h(dt.x), Slm=u2h(dt.y), Cph=u2h(dt.z), Sph=u2h(dt.w);
    const h2 nSlm=negh(Slm), nSph=negh(Sph);
    const h2 tu1H = L4 ? ust0h : nust0h;
    const h2 tu3H = L2 ? ust0h : nust0h;
    const h2 tu5H = L0 ? ust0h : nust0h;

    // ========== Phase 1 (real, per element A=(a0,a1) B=(a2,a3)) ==========
#define RY_L(q, M) do { FOR_E { \
    h2 oA = f2h(sx<M>(h2f(A[e]))), oB = f2h(sx<M>(h2f(B[e]))); \
    A[e] = fma2h(cH[e][q], A[e], tsH[e][q]*oA); \
    B[e] = fma2h(cH[e][q], B[e], tsH[e][q]*oB); } \
} while(0)

#define RINGF() do { FOR_E { \
    float TA = h2f(pb ? B[e] : A[e]); \
    float TS = h2f(swp(pb ? A[e] : B[e])); \
    float u0 = bperm(ba0, TA), u1 = bperm(ba1, TA); \
    float w0 = bperm(ba0, TS), w1 = bperm(ba1, TS); \
    A[e] = (h2){ f2h(u0).x, f2h(u1).y }; \
    B[e] = (h2){ f2h(w0).x, f2h(w1).y }; } \
} while(0)

    RINGF();
#pragma unroll
    for(int cyc=0;cyc<3;++cyc){
        RY_L(0,32); RY_L(1,16); RY_L(2,8); RY_L(3,4); RY_L(4,2); RY_L(5,1);
        FOR_E { h2 nA = fma2h(c6h[e], A[e], ns6h[e]*B[e]);     // RY q6
                h2 nB = fma2h(s6h[e], A[e], c6h[e]*B[e]);
                A[e]=nA; B[e]=nB; }
        FOR_E { A[e] = fma2h(c7h[e], A[e], sv7h[e]*swp(A[e])); // RY q7
                B[e] = fma2h(c7h[e], B[e], sv7h[e]*swp(B[e])); }
        RINGF();
    }

    // ========== Phase 2 (complex, f16x2) ==========
    h2 RA[NE], RB[NE], IA[NE], IB[NE];
    FOR_E { RA[e]=A[e]; RB[e]=B[e]; IA[e]=(h2){0,0}; IB[e]=(h2){0,0}; }

#define SHF4(M) h2 oRA[NE], oIA[NE], oRB[NE], oIB[NE]; \
    FOR_E { oRA[e]=f2h(sx<M>(h2f(RA[e]))); oIA[e]=f2h(sx<M>(h2f(IA[e]))); \
            oRB[e]=f2h(sx<M>(h2f(RB[e]))); oIB[e]=f2h(sx<M>(h2f(IB[e]))); }
#define CRX_LL(CSH, M, cc, sn, nsn) do { \
    const bool ct = (l >> (CSH)) & 1; \
    SHF4(M) \
    if (ct) { FOR_E { \
        RA[e] = fma2h(cc, RA[e], (sn)*oIA[e]); IA[e] = fma2h(cc, IA[e], (nsn)*oRA[e]); \
        RB[e] = fma2h(cc, RB[e], (sn)*oIB[e]); IB[e] = fma2h(cc, IB[e], (nsn)*oRB[e]); } } \
} while(0)
#define RYC0(M, T) do { \
    SHF4(M) \
    FOR_E { \
    RA[e] = fma2h(uct0h, RA[e], (T)*oRA[e]); IA[e] = fma2h(uct0h, IA[e], (T)*oIA[e]); \
    RB[e] = fma2h(uct0h, RB[e], (T)*oRB[e]); IB[e] = fma2h(uct0h, IB[e], (T)*oIB[e]); } \
} while(0)

    // Layer 0, sublayer 1: (0,1) real-state fast path; (2,3); (4,5); (6,7)
    {   h2 oA[NE], oB[NE];
        FOR_E { oA[e]=f2h(sx<16>(h2f(RA[e]))); oB[e]=f2h(sx<16>(h2f(RB[e]))); }
        if (L5){ FOR_E {
            IA[e] = nsn0h*oA[e]; RA[e] = cc0h*RA[e];
            IB[e] = nsn0h*oB[e]; RB[e] = cc0h*RB[e]; } }
    }
    CRX_LL(3, 4, cc0h, sn0h, nsn0h);     // (2,3)
    CRX_LL(1, 1, cc0h, sn0h, nsn0h);     // (4,5)
    FOR_E {                               // (6,7): within B pair
        h2 oI = swp(IB[e]), oR = swp(RB[e]);
        RB[e] = fma2h(cc0h, RB[e], sn0h*oI);
        IB[e] = fma2h(cc0h, IB[e], nsn0h*oR);
    }
    // sublayer 2: (1,2); (3,4); (5,6)
    CRX_LL(4, 8, cc0h, sn0h, nsn0h);     // (1,2)
    CRX_LL(2, 2, cc0h, sn0h, nsn0h);     // (3,4)
    if (L0) { FOR_E {                     // (5,6): A<->B elementwise
        h2 nRA = fma2h(cc0h, RA[e], sn0h*IB[e]);
        h2 nRB = fma2h(cc0h, RB[e], sn0h*IA[e]);
        h2 nIA = fma2h(cc0h, IA[e], nsn0h*RB[e]);
        h2 nIB = fma2h(cc0h, IB[e], nsn0h*RA[e]);
        RA[e]=nRA; RB[e]=nRB; IA[e]=nIA; IB[e]=nIB; } }
    // fused L0 U3 on q1,q3,q5,q7: [D2(ph0)][RY(th0)x4][D1(lm0)]
    FOR_E { cmulh(RA[e],IA[e],Clm,Slm,nSlm); cmulh(RB[e],IB[e],Clm,Slm,nSlm); }
    RYC0(16, tu1H);
    RYC0(4,  tu3H);
    RYC0(1,  tu5H);
    FOR_E {                               // RY q7 (component)
        h2 sA=swp(RA[e]), sB=swp(RB[e]), tA=swp(IA[e]), tB=swp(IB[e]);
        RA[e] = fma2h(uct0h, RA[e], usv0h*sA); RB[e] = fma2h(uct0h, RB[e], usv0h*sB);
        IA[e] = fma2h(uct0h, IA[e], usv0h*tA); IB[e] = fma2h(uct0h, IB[e], usv0h*tB);
    }
    FOR_E { cmulh(RA[e],IA[e],Cph,Sph,nSph); cmulh(RB[e],IB[e],Cph,Sph,nSph); }

    // Layer 1: CRX (1,3),(5,7),(3,5); U3 on q3, q7
    CRX_LL(4, 4, cc1h, sn1h, nsn1h);     // (1,3)
    if (L0) { FOR_E {                     // (5,7): component pair
        h2 sIA=swp(IA[e]), sRA=swp(RA[e]), sIB=swp(IB[e]), sRB=swp(RB[e]);
        RA[e] = fma2h(cc1h, RA[e], sn1h*sIA); IA[e] = fma2h(cc1h, IA[e], nsn1h*sRA);
        RB[e] = fma2h(cc1h, RB[e], sn1h*sIB); IB[e] = fma2h(cc1h, IB[e], nsn1h*sRB); } }
    CRX_LL(2, 1, cc1h, sn1h, nsn1h);     // (3,5)
    {   // U3 L1 on q3: D(lm1), RY(th1), D(ph1)
        if (L2){ FOR_E { cmulh(RA[e],IA[e],cl1h,sl1h,nsl1h); cmulh(RB[e],IB[e],cl1h,sl1h,nsl1h); } }
        h2 T = L2 ? ust1h : nust1h;
        SHF4(4)
        FOR_E {
            RA[e] = fma2h(uct1h, RA[e], T*oRA[e]); IA[e] = fma2h(uct1h, IA[e], T*oIA[e]);
            RB[e] = fma2h(uct1h, RB[e], T*oRB[e]); IB[e] = fma2h(uct1h, IB[e], T*oIB[e]);
        }
        if (L2){ FOR_E { cmulh(RA[e],IA[e],cp1h,sp1h,nsp1h); cmulh(RB[e],IB[e],cp1h,sp1h,nsp1h); } }
    }
    FOR_E {   // U3 L1 on q7: direct complex 2x2 (component-mixed constants)
        h2 sR=swp(RA[e]), sI=swp(IA[e]);
        h2 nR = fma2h(E3h,sI, fma2h(E2h,IA[e], fma2h(E1h,sR, E0h*RA[e])));
        h2 nI = fma2h(G3h,sR, fma2h(G2h,RA[e], fma2h(E1h,sI, E0h*IA[e])));
        RA[e]=nR; IA[e]=nI;
        h2 sR2=swp(RB[e]), sI2=swp(IB[e]);
        h2 nR2 = fma2h(E3h,sI2, fma2h(E2h,IB[e], fma2h(E1h,sR2, E0h*RB[e])));
        h2 nI2 = fma2h(G3h,sR2, fma2h(G2h,RB[e], fma2h(E1h,sI2, E0h*IB[e])));
        RB[e]=nR2; IB[e]=nI2;
    }

    // ========== expvals (fp32) + merged MLP ==========
    float f0[NE], f1[NE];
    FOR_E {
        float r0=(float)RA[e].x, r1=(float)RA[e].y, r2=(float)RB[e].x, r3=(float)RB[e].y;
        float i0=(float)IA[e].x, i1=(float)IA[e].y, i2=(float)IB[e].x, i3=(float)IB[e].y;
        float n0=fmaf(i0,i0,r0*r0), n1=fmaf(i1,i1,r1*r1);
        float n2=fmaf(i2,i2,r2*r2), n3=fmaf(i3,i3,r3*r3);
        float tot=(n0+n1)+(n2+n3);
        f0[e] = L2 ? -tot : tot;          // Z(q3): lane bit2
        f1[e] = (n0-n1)+(n2-n3);          // Z(q7): component
    }
    FOR_E { f0[e] += sx<1>(f0[e]);  f1[e] += sx<1>(f1[e]);  }
    FOR_E { f0[e] += sx<2>(f0[e]);  f1[e] += sx<2>(f1[e]);  }
    FOR_E { f0[e] += sx<4>(f0[e]);  f1[e] += sx<4>(f1[e]);  }
    FOR_E { f0[e] += sx<8>(f0[e]);  f1[e] += sx<8>(f1[e]);  }
    FOR_E { f0[e] += sx<16>(f0[e]); f1[e] += sx<16>(f1[e]); }
    FOR_E { f0[e] += sx<32>(f0[e]); f1[e] += sx<32>(f1[e]); }

    // merged tail: row r (l>>4) handles element r; one exp chain.
    const int k = l & 15;
    const int row = l >> 4;
    float Fx = f0[0], Fy = f1[0];
    Fx = (row==1) ? f0[1] : Fx;  Fy = (row==1) ? f1[1] : Fy;
    Fx = (row==2) ? f0[2] : Fx;  Fy = (row==2) ? f1[2] : Fy;
    Fx = (row==3) ? f0[3] : Fx;  Fy = (row==3) ? f1[3] : Fy;
    float contrib = 0.0f;
    if (k < 10) {
        float z = fmaf(Fx, w1[k], fmaf(Fy, w1[10+k], b1[k]));
        float ex = __expf(2.0f*z);
        contrib = ((ex-1.0f)/(ex+1.0f)) * w2[k];
    }
    contrib += sx<1>(contrib);
    contrib += sx<2>(contrib);
    contrib += sx<4>(contrib);
    contrib += sx<8>(contrib);
    if (k == 0) {
        float a = contrib + b2[0];
        out[e0 + row] = 1.0f/(1.0f + __expf(-a));
    }
}

extern "C" void kernel_launch(void* const* d_in, const int* in_sizes, int n_in,
                              void* d_out, int out_size, void* d_ws, size_t ws_size,
                              hipStream_t stream) {
    const float* x   = (const float*)d_in[0];
    const float* crx = (const float*)d_in[1];
    const float* u3p = (const float*)d_in[2];
    const float* w1  = (const float*)d_in[3];
    const float* b1  = (const float*)d_in[4];
    const float* w2  = (const float*)d_in[5];
    const float* b2  = (const float*)d_in[6];
    float* out = (float*)d_out;
    unsigned* ws = (unsigned*)d_ws;

    const int B = in_sizes[0] / NQ;              // 65536
    hipLaunchKernelGGL(qcnn_prep, dim3(1), dim3(64), 0, stream, crx, u3p, ws);
    const int waves = (B + NE - 1) / NE;         // 4 elements per wave
    const int wavesPerBlock = 4;
    const int grid = (waves + wavesPerBlock - 1) / wavesPerBlock;
    hipLaunchKernelGGL(qcnn_kernel, dim3(grid), dim3(256), 0, stream,
                       x, ws, w1, b1, w2, b2, out, B);
}